// Round 6
// baseline (265.141 us; speedup 1.0000x reference)
//
#include <hip/hip_runtime.h>
#include <cstdint>

typedef unsigned short ushort_t;
typedef short short8 __attribute__((ext_vector_type(8)));
typedef float f32x4 __attribute__((ext_vector_type(4)));
typedef float float4v __attribute__((ext_vector_type(4)));
typedef unsigned int uint2v __attribute__((ext_vector_type(2)));

#define DDIM 1024
#define HH 16
#define HEADK 64
#define BB 2
#define SS 2048

#if __has_builtin(__builtin_amdgcn_exp2f)
#define EXP2F(x) __builtin_amdgcn_exp2f(x)
#else
#define EXP2F(x) exp2f(x)
#endif

__device__ __forceinline__ ushort_t f2bf(float f) {
  union { float f; uint32_t u; } c; c.f = f;
  uint32_t u = c.u;
  u += 0x7fffu + ((u >> 16) & 1u);
  return (ushort_t)(u >> 16);
}

// truncation-pack two fp32 -> bf16x2 (1 v_perm). Bias cancels in l-normalization.
__device__ __forceinline__ uint32_t pkbf_trunc(float a, float b) {
  union { float f; uint32_t u; } ca, cb;
  ca.f = a; cb.f = b;
  return __builtin_amdgcn_perm(cb.u, ca.u, 0x07060302);
}

__device__ __forceinline__ uint32_t pkbf_rne(float a, float b) {
  return (uint32_t)f2bf(a) | ((uint32_t)f2bf(b) << 16);
}

__device__ __forceinline__ void glds16(const ushort_t* gp, ushort_t* lp) {
  __builtin_amdgcn_global_load_lds(
      (const __attribute__((address_space(1))) uint32_t*)gp,
      (__attribute__((address_space(3))) uint32_t*)lp, 16, 0, 0);
}

// ---------------- fp32 -> bf16 convert, 3 tensors in one launch ----------------
__global__ void cvt3_kernel(const float* __restrict__ s0, ushort_t* __restrict__ d0, int n0,
                            const float* __restrict__ s1, ushort_t* __restrict__ d1, int n1,
                            const float* __restrict__ s2, ushort_t* __restrict__ d2, int n2) {
  int i = blockIdx.x * blockDim.x + threadIdx.x;
  const float* src; ushort_t* dst; int k;
  if (i < n0) { src = s0; dst = d0; k = i; }
  else if (i < n0 + n1) { src = s1; dst = d1; k = i - n0; }
  else if (i < n0 + n1 + n2) { src = s2; dst = d2; k = i - n0 - n1; }
  else return;
  float4v v = ((const float4v*)src)[k];
  uint2v o; o[0] = pkbf_rne(v[0], v[1]); o[1] = pkbf_rne(v[2], v[3]);
  ((uint2v*)dst)[k] = o;
}

// ---------------- NT GEMM: C[M,N] = A[M,Kd] * Bm[N,Kd]^T + bias ----------------
// MODE 0: scatter-write bf16 into qkv: Q,K as [t][B][H][S][64]; V as [2][B][H][64][S].
//         Q pre-scaled by 0.125*log2(e) (exp2 domain for softmax).
// MODE 1: write fp32 C row-major
template <int MODE>
__global__ __launch_bounds__(256) void gemm_nt(
    const ushort_t* __restrict__ A, const ushort_t* __restrict__ Bm,
    const float* __restrict__ bias, float* __restrict__ Cout,
    ushort_t* __restrict__ Cbf, int M, int N, int Kd) {
  __shared__ ushort_t As[128 * 64];
  __shared__ ushort_t Bs[128 * 64];
  const int tid = threadIdx.x;
  const int wv = tid >> 6, lane = tid & 63;
  const int l15 = lane & 15, quad = lane >> 4;
  const int wm = wv >> 1, wn = wv & 1;
  const int tm0 = blockIdx.y * 128, tn0 = blockIdx.x * 128;

  f32x4 acc[4][4];
#pragma unroll
  for (int i = 0; i < 4; ++i)
#pragma unroll
    for (int j = 0; j < 4; ++j) acc[i][j] = (f32x4){0.f, 0.f, 0.f, 0.f};

  const int lrow = lane >> 3;
  const int gcb = (lane & 7) ^ lrow;

  for (int k0 = 0; k0 < Kd; k0 += 64) {
#pragma unroll
    for (int c = 0; c < 4; ++c) {
      int seg = wv * 4 + c;
      glds16(A + (size_t)(tm0 + seg * 8 + lrow) * Kd + k0 + gcb * 8,
             As + seg * 512);
    }
#pragma unroll
    for (int c = 0; c < 4; ++c) {
      int seg = wv * 4 + c;
      glds16(Bm + (size_t)(tn0 + seg * 8 + lrow) * Kd + k0 + gcb * 8,
             Bs + seg * 512);
    }
    __syncthreads();
#pragma unroll
    for (int kk = 0; kk < 64; kk += 32) {
      short8 af[4], bfr[4];
#pragma unroll
      for (int i = 0; i < 4; ++i) {
        int r = wm * 64 + i * 16 + l15;
        int cb = (kk >> 3) + quad;
        af[i] = *(const short8*)(As + r * 64 + ((cb ^ (l15 & 7)) << 3));
      }
#pragma unroll
      for (int j = 0; j < 4; ++j) {
        int r = wn * 64 + j * 16 + l15;
        int cb = (kk >> 3) + quad;
        bfr[j] = *(const short8*)(Bs + r * 64 + ((cb ^ (l15 & 7)) << 3));
      }
#pragma unroll
      for (int i = 0; i < 4; ++i)
#pragma unroll
        for (int j = 0; j < 4; ++j)
          acc[i][j] = __builtin_amdgcn_mfma_f32_16x16x32_bf16(
              af[i], bfr[j], acc[i][j], 0, 0, 0);
    }
    __syncthreads();
  }

#pragma unroll
  for (int j = 0; j < 4; ++j) {
    int col = tn0 + wn * 64 + j * 16 + l15;
    float bv = bias[col];
#pragma unroll
    for (int i = 0; i < 4; ++i) {
      int row0 = tm0 + wm * 64 + i * 16 + quad * 4;
#pragma unroll
      for (int r = 0; r < 4; ++r) {
        float v = acc[i][j][r] + bv;
        int row = row0 + r;
        if (MODE == 0) {
          int t = col >> 10, hh = (col >> 6) & 15, kk2 = col & 63;
          int b = row >> 11, s = row & 2047;
          float vv = (t == 0) ? v * 0.18033688f : v;  // 0.125*log2(e)
          size_t base = (((size_t)t * BB + b) * HH + hh) * ((size_t)SS * HEADK);
          size_t idx = (t == 2) ? base + (size_t)kk2 * SS + s
                                : base + (size_t)s * HEADK + kk2;
          Cbf[idx] = f2bf(vv);
        } else {
          Cout[(size_t)row * N + col] = v;
        }
      }
    }
  }
}

// ---------------- flash attention, barrier-free ----------------
// 1D grid of 512 blocks: pair p = bid&31 (h=p>>1, b=p&1) spreads KV streams
// round-robin over XCDs; qt = bid>>5 gives 128 q-rows/block.
// 4 waves x 32 q-rows. KV fragments loaded straight from global into registers
// (identical addresses across the 4 waves -> L1/L2 reuse), software-prefetched
// one tile ahead. LDS holds only the per-wave P buffer -> NO barriers of any
// kind (P slab is per-wave; same-wave LDS RAW is ordered by lgkmcnt).
__global__ __launch_bounds__(256, 2) void attn_kernel(
    const ushort_t* __restrict__ qkv, ushort_t* __restrict__ ob) {
  __shared__ ushort_t Pw[4][32 * 64];   // per-wave P [qrow][pos], swizzled

  const int bid = blockIdx.x;
  const int p = bid & 31, qt = bid >> 5;
  const int h = p >> 1, b = p & 1;
  const int tid = threadIdx.x;
  const int wv = tid >> 6, lane = tid & 63;
  const int l15 = lane & 15, quad = lane >> 4;

  const size_t hstride = (size_t)SS * HEADK;
  const ushort_t* Qg = qkv + ((size_t)(0 * BB + b) * HH + h) * hstride;
  const ushort_t* Kg = qkv + ((size_t)(1 * BB + b) * HH + h) * hstride;
  const ushort_t* Vg = qkv + ((size_t)(2 * BB + b) * HH + h) * hstride; // [64][2048]

  // Q fragments (pre-scaled by 0.125*log2e in GEMM1): B-operand, qrow = l15
  short8 qf[2][2];
#pragma unroll
  for (int mi = 0; mi < 2; ++mi)
#pragma unroll
    for (int kc = 0; kc < 2; ++kc)
      qf[mi][kc] = *(const short8*)(
          Qg + (size_t)(qt * 128 + wv * 32 + mi * 16 + l15) * 64 + kc * 32 +
          quad * 8);

  const short ONE = (short)0x3F80;  // bf16 1.0
  short8 ones = {ONE, ONE, ONE, ONE, ONE, ONE, ONE, ONE};

  f32x4 oat[2][4];  // O^T: rows feat=cf*16+quad*4+r, col qrow=l15
  f32x4 loa[2];     // l: col qrow=l15
#pragma unroll
  for (int mi = 0; mi < 2; ++mi) {
    loa[mi] = (f32x4){0.f, 0.f, 0.f, 0.f};
#pragma unroll
    for (int c = 0; c < 4; ++c) oat[mi][c] = (f32x4){0.f, 0.f, 0.f, 0.f};
  }

  // K/V fragments in registers (A-operand): lane holds row (cf*16+l15),
  // k-chunk quad*8 within k-half kc*32. Same addresses for all 4 waves.
  short8 kf[4][2], vf[4][2];
#pragma unroll
  for (int cf = 0; cf < 4; ++cf)
#pragma unroll
    for (int kc = 0; kc < 2; ++kc) {
      kf[cf][kc] = *(const short8*)(
          Kg + (size_t)(cf * 16 + l15) * 64 + kc * 32 + quad * 8);
      vf[cf][kc] = *(const short8*)(
          Vg + (size_t)(cf * 16 + l15) * SS + kc * 32 + quad * 8);
    }

  for (int j = 0; j < 32; ++j) {
    // S^T frags: rows pos = cf*16+quad*4+r, col qrow = l15
    f32x4 st[2][4];
#pragma unroll
    for (int cf = 0; cf < 4; ++cf)
#pragma unroll
      for (int mi = 0; mi < 2; ++mi) {
        f32x4 z = (f32x4){0.f, 0.f, 0.f, 0.f};
        z = __builtin_amdgcn_mfma_f32_16x16x32_bf16(kf[cf][0], qf[mi][0], z, 0, 0, 0);
        z = __builtin_amdgcn_mfma_f32_16x16x32_bf16(kf[cf][1], qf[mi][1], z, 0, 0, 0);
        st[mi][cf] = z;
      }

    // prefetch next K tile (wraps at the end; value unused on last iter)
    const int jn = (j + 1) & 31;
#pragma unroll
    for (int cf = 0; cf < 4; ++cf)
#pragma unroll
      for (int kc = 0; kc < 2; ++kc)
        kf[cf][kc] = *(const short8*)(
            Kg + (size_t)(jn * 64 + cf * 16 + l15) * 64 + kc * 32 + quad * 8);

    // P = exp2(S^T), pack, write to per-wave LDS [qrow][pos] (swizzled, b64)
#pragma unroll
    for (int mi = 0; mi < 2; ++mi)
#pragma unroll
      for (int cf = 0; cf < 4; ++cf) {
        float e0 = EXP2F(st[mi][cf][0]);
        float e1 = EXP2F(st[mi][cf][1]);
        float e2 = EXP2F(st[mi][cf][2]);
        float e3 = EXP2F(st[mi][cf][3]);
        uint2v dw;
        dw[0] = pkbf_trunc(e0, e1);
        dw[1] = pkbf_trunc(e2, e3);
        int row = mi * 16 + l15;
        int bb = 2 * cf + (quad >> 1);
        *(uint2v*)(&Pw[wv][row * 64 + ((bb ^ (l15 & 7)) << 3) +
                           (quad & 1) * 4]) = dw;
      }

    // read P as B-operand frags (rows qrow=l15, k=pos)
    short8 pa[2][2];
#pragma unroll
    for (int mi = 0; mi < 2; ++mi)
#pragma unroll
      for (int kc = 0; kc < 2; ++kc)
        pa[mi][kc] = *(const short8*)(&Pw[wv][(mi * 16 + l15) * 64 +
                                              (((kc * 4 + quad) ^ (l15 & 7))
                                               << 3)]);

    // O^T += V^T-frag * P ; l += ones * P
#pragma unroll
    for (int cf = 0; cf < 4; ++cf)
#pragma unroll
      for (int mi = 0; mi < 2; ++mi) {
        oat[mi][cf] = __builtin_amdgcn_mfma_f32_16x16x32_bf16(
            vf[cf][0], pa[mi][0], oat[mi][cf], 0, 0, 0);
        oat[mi][cf] = __builtin_amdgcn_mfma_f32_16x16x32_bf16(
            vf[cf][1], pa[mi][1], oat[mi][cf], 0, 0, 0);
      }
#pragma unroll
    for (int mi = 0; mi < 2; ++mi) {
      loa[mi] = __builtin_amdgcn_mfma_f32_16x16x32_bf16(ones, pa[mi][0],
                                                        loa[mi], 0, 0, 0);
      loa[mi] = __builtin_amdgcn_mfma_f32_16x16x32_bf16(ones, pa[mi][1],
                                                        loa[mi], 0, 0, 0);
    }

    // prefetch next V tile
#pragma unroll
    for (int cf = 0; cf < 4; ++cf)
#pragma unroll
      for (int kc = 0; kc < 2; ++kc)
        vf[cf][kc] = *(const short8*)(
            Vg + (size_t)(cf * 16 + l15) * SS + jn * 64 + kc * 32 + quad * 8);
  }

  // epilogue: normalize, transpose O^T -> [qrow][feat] via Pw, coalesced store
#pragma unroll
  for (int mi = 0; mi < 2; ++mi) {
    float inv = 1.0f / loa[mi][0];
#pragma unroll
    for (int cf = 0; cf < 4; ++cf) {
      uint2v dw;
      dw[0] = pkbf_rne(oat[mi][cf][0] * inv, oat[mi][cf][1] * inv);
      dw[1] = pkbf_rne(oat[mi][cf][2] * inv, oat[mi][cf][3] * inv);
      int row = mi * 16 + l15;
      int bb = 2 * cf + (quad >> 1);
      *(uint2v*)(&Pw[wv][row * 64 + ((bb ^ (l15 & 7)) << 3) + (quad & 1) * 4]) =
          dw;
    }
  }
  const int rr = lane >> 1, half = lane & 1;
#pragma unroll
  for (int c = 0; c < 4; ++c) {
    short8 ov = *(const short8*)(&Pw[wv][rr * 64 +
                                         (((half * 4 + c) ^ (rr & 7)) << 3)]);
    int row = qt * 128 + wv * 32 + rr;
    *(short8*)(&ob[(size_t)(b * SS + row) * DDIM + h * 64 + half * 32 +
                   c * 8]) = ov;
  }
}

extern "C" void kernel_launch(void* const* d_in, const int* in_sizes, int n_in,
                              void* d_out, int out_size, void* d_ws,
                              size_t ws_size, hipStream_t stream) {
  const float* x = (const float*)d_in[0];
  const float* Wqkv = (const float*)d_in[1];
  const float* bqkv = (const float*)d_in[2];
  const float* Wproj = (const float*)d_in[3];
  const float* bproj = (const float*)d_in[4];
  float* out = (float*)d_out;

  ushort_t* xb = (ushort_t*)d_ws;
  ushort_t* wqb = xb + (size_t)4096 * 1024;
  ushort_t* wpb = wqb + (size_t)3072 * 1024;
  ushort_t* qkvb = wpb + (size_t)1024 * 1024;
  ushort_t* obuf = qkvb + (size_t)3 * BB * HH * SS * HEADK;

  const int n0 = 4096 * 1024 / 4, n1 = 3072 * 1024 / 4, n2 = 1024 * 1024 / 4;
  cvt3_kernel<<<(n0 + n1 + n2 + 255) / 256, 256, 0, stream>>>(
      x, xb, n0, Wqkv, wqb, n1, Wproj, wpb, n2);
  gemm_nt<0><<<dim3(3072 / 128, 4096 / 128), 256, 0, stream>>>(
      xb, wqb, bqkv, nullptr, qkvb, 4096, 3072, 1024);
  attn_kernel<<<dim3(512), 256, 0, stream>>>(qkvb, obuf);
  gemm_nt<1><<<dim3(1024 / 128, 4096 / 128), 256, 0, stream>>>(
      obuf, wpb, bproj, out, nullptr, 4096, 1024, 1024);
}

// Round 8
// 212.502 us; speedup vs baseline: 1.2477x; 1.2477x over previous
//
#include <hip/hip_runtime.h>
#include <cstdint>

typedef unsigned short ushort_t;
typedef short short8 __attribute__((ext_vector_type(8)));
typedef float f32x4 __attribute__((ext_vector_type(4)));
typedef float float4v __attribute__((ext_vector_type(4)));
typedef unsigned int uint2v __attribute__((ext_vector_type(2)));

#define DDIM 1024
#define HH 16
#define HEADK 64
#define BB 2
#define SS 2048

#if __has_builtin(__builtin_amdgcn_exp2f)
#define EXP2F(x) __builtin_amdgcn_exp2f(x)
#else
#define EXP2F(x) exp2f(x)
#endif

__device__ __forceinline__ ushort_t f2bf(float f) {
  union { float f; uint32_t u; } c; c.f = f;
  uint32_t u = c.u;
  u += 0x7fffu + ((u >> 16) & 1u);
  return (ushort_t)(u >> 16);
}

// truncation-pack two fp32 -> bf16x2 (1 v_perm). Bias cancels in l-normalization.
__device__ __forceinline__ uint32_t pkbf_trunc(float a, float b) {
  union { float f; uint32_t u; } ca, cb;
  ca.f = a; cb.f = b;
  return __builtin_amdgcn_perm(cb.u, ca.u, 0x07060302);
}

__device__ __forceinline__ uint32_t pkbf_rne(float a, float b) {
  return (uint32_t)f2bf(a) | ((uint32_t)f2bf(b) << 16);
}

__device__ __forceinline__ void glds16(const ushort_t* gp, ushort_t* lp) {
  __builtin_amdgcn_global_load_lds(
      (const __attribute__((address_space(1))) uint32_t*)gp,
      (__attribute__((address_space(3))) uint32_t*)lp, 16, 0, 0);
}

// ---------------- fp32 -> bf16 convert, 3 tensors in one launch ----------------
__global__ void cvt3_kernel(const float* __restrict__ s0, ushort_t* __restrict__ d0, int n0,
                            const float* __restrict__ s1, ushort_t* __restrict__ d1, int n1,
                            const float* __restrict__ s2, ushort_t* __restrict__ d2, int n2) {
  int i = blockIdx.x * blockDim.x + threadIdx.x;
  const float* src; ushort_t* dst; int k;
  if (i < n0) { src = s0; dst = d0; k = i; }
  else if (i < n0 + n1) { src = s1; dst = d1; k = i - n0; }
  else if (i < n0 + n1 + n2) { src = s2; dst = d2; k = i - n0 - n1; }
  else return;
  float4v v = ((const float4v*)src)[k];
  uint2v o; o[0] = pkbf_rne(v[0], v[1]); o[1] = pkbf_rne(v[2], v[3]);
  ((uint2v*)dst)[k] = o;
}

// ---------------- NT GEMM: C[M,N] = A[M,Kd] * Bm[N,Kd]^T + bias ----------------
// MODE 0: scatter-write bf16 into qkv: Q,K as [t][B][H][S][64]; V as [2][B][H][64][S].
//         Q pre-scaled by 0.125*log2(e) (exp2 domain for softmax).
// MODE 1: write fp32 C row-major
template <int MODE>
__global__ __launch_bounds__(256) void gemm_nt(
    const ushort_t* __restrict__ A, const ushort_t* __restrict__ Bm,
    const float* __restrict__ bias, float* __restrict__ Cout,
    ushort_t* __restrict__ Cbf, int M, int N, int Kd) {
  __shared__ ushort_t As[128 * 64];
  __shared__ ushort_t Bs[128 * 64];
  const int tid = threadIdx.x;
  const int wv = tid >> 6, lane = tid & 63;
  const int l15 = lane & 15, quad = lane >> 4;
  const int wm = wv >> 1, wn = wv & 1;
  const int tm0 = blockIdx.y * 128, tn0 = blockIdx.x * 128;

  f32x4 acc[4][4];
#pragma unroll
  for (int i = 0; i < 4; ++i)
#pragma unroll
    for (int j = 0; j < 4; ++j) acc[i][j] = (f32x4){0.f, 0.f, 0.f, 0.f};

  const int lrow = lane >> 3;
  const int gcb = (lane & 7) ^ lrow;

  for (int k0 = 0; k0 < Kd; k0 += 64) {
#pragma unroll
    for (int c = 0; c < 4; ++c) {
      int seg = wv * 4 + c;
      glds16(A + (size_t)(tm0 + seg * 8 + lrow) * Kd + k0 + gcb * 8,
             As + seg * 512);
    }
#pragma unroll
    for (int c = 0; c < 4; ++c) {
      int seg = wv * 4 + c;
      glds16(Bm + (size_t)(tn0 + seg * 8 + lrow) * Kd + k0 + gcb * 8,
             Bs + seg * 512);
    }
    __syncthreads();
#pragma unroll
    for (int kk = 0; kk < 64; kk += 32) {
      short8 af[4], bfr[4];
#pragma unroll
      for (int i = 0; i < 4; ++i) {
        int r = wm * 64 + i * 16 + l15;
        int cb = (kk >> 3) + quad;
        af[i] = *(const short8*)(As + r * 64 + ((cb ^ (l15 & 7)) << 3));
      }
#pragma unroll
      for (int j = 0; j < 4; ++j) {
        int r = wn * 64 + j * 16 + l15;
        int cb = (kk >> 3) + quad;
        bfr[j] = *(const short8*)(Bs + r * 64 + ((cb ^ (l15 & 7)) << 3));
      }
#pragma unroll
      for (int i = 0; i < 4; ++i)
#pragma unroll
        for (int j = 0; j < 4; ++j)
          acc[i][j] = __builtin_amdgcn_mfma_f32_16x16x32_bf16(
              af[i], bfr[j], acc[i][j], 0, 0, 0);
    }
    __syncthreads();
  }

#pragma unroll
  for (int j = 0; j < 4; ++j) {
    int col = tn0 + wn * 64 + j * 16 + l15;
    float bv = bias[col];
#pragma unroll
    for (int i = 0; i < 4; ++i) {
      int row0 = tm0 + wm * 64 + i * 16 + quad * 4;
#pragma unroll
      for (int r = 0; r < 4; ++r) {
        float v = acc[i][j][r] + bv;
        int row = row0 + r;
        if (MODE == 0) {
          int t = col >> 10, hh = (col >> 6) & 15, kk2 = col & 63;
          int b = row >> 11, s = row & 2047;
          float vv = (t == 0) ? v * 0.18033688f : v;  // 0.125*log2(e)
          size_t base = (((size_t)t * BB + b) * HH + hh) * ((size_t)SS * HEADK);
          size_t idx = (t == 2) ? base + (size_t)kk2 * SS + s
                                : base + (size_t)s * HEADK + kk2;
          Cbf[idx] = f2bf(vv);
        } else {
          Cout[(size_t)row * N + col] = v;
        }
      }
    }
  }
}

// ---------------- flash attention ----------------
// grid 512 blocks: p=bid&31 (h=p>>1,b=p&1), qt=bid>>5 -> 128 q-rows/block.
// 2 waves x 64 q-rows (4 m-frags each): halves per-row K/V LDS re-reads vs
// 32-row waves (LDS pipe is the binding resource — round-3 analysis).
// KV tile 64 double-buffered via glds16; S^T trick; ones-MFMA l; per-wave P.
__global__ __launch_bounds__(128, 1) void attn_kernel(
    const ushort_t* __restrict__ qkv, ushort_t* __restrict__ ob) {
  __shared__ ushort_t Kt[2][64 * 64];   // [pos][feat], XOR-swizzled 16B blocks
  __shared__ ushort_t Vt[2][64 * 64];   // [feat][pos], XOR-swizzled 16B blocks
  __shared__ ushort_t Pw[2][64 * 64];   // per-wave P [qrow][pos], swizzled

  const int bid = blockIdx.x;
  const int p = bid & 31, qt = bid >> 5;
  const int h = p >> 1, b = p & 1;
  const int tid = threadIdx.x;
  const int wv = tid >> 6, lane = tid & 63;
  const int l15 = lane & 15, quad = lane >> 4;

  const size_t hstride = (size_t)SS * HEADK;
  const ushort_t* Qg = qkv + ((size_t)(0 * BB + b) * HH + h) * hstride;
  const ushort_t* Kg = qkv + ((size_t)(1 * BB + b) * HH + h) * hstride;
  const ushort_t* Vg = qkv + ((size_t)(2 * BB + b) * HH + h) * hstride; // [64][2048]

  // Q fragments (pre-scaled by 0.125*log2e in GEMM1): B-operand, qrow = l15
  short8 qf[4][2];
#pragma unroll
  for (int mi = 0; mi < 4; ++mi)
#pragma unroll
    for (int kc = 0; kc < 2; ++kc)
      qf[mi][kc] = *(const short8*)(
          Qg + (size_t)(qt * 128 + wv * 64 + mi * 16 + l15) * 64 + kc * 32 +
          quad * 8);

  const short ONE = (short)0x3F80;  // bf16 1.0
  short8 ones = {ONE, ONE, ONE, ONE, ONE, ONE, ONE, ONE};

  f32x4 oat[4][4];  // O^T: rows feat=cf*16+quad*4+r, col qrow=l15
  f32x4 loa[4];     // l: col qrow=l15
#pragma unroll
  for (int mi = 0; mi < 4; ++mi) {
    loa[mi] = (f32x4){0.f, 0.f, 0.f, 0.f};
#pragma unroll
    for (int c = 0; c < 4; ++c) oat[mi][c] = (f32x4){0.f, 0.f, 0.f, 0.f};
  }

  const int lrow = lane >> 3, gcb = (lane & 7) ^ lrow;

  auto stage = [&](int jj, int db) {
#pragma unroll
    for (int c = 0; c < 4; ++c) {
      int seg = wv * 4 + c;  // 0..7 over 2 waves
      glds16(Kg + (size_t)(jj * 64 + seg * 8 + lrow) * 64 + gcb * 8,
             &Kt[db][seg * 512]);
    }
#pragma unroll
    for (int c = 0; c < 4; ++c) {
      int seg = wv * 4 + c;
      glds16(Vg + (size_t)(seg * 8 + lrow) * SS + jj * 64 + gcb * 8,
             &Vt[db][seg * 512]);
    }
  };

  stage(0, 0);

  for (int j = 0; j < 32; ++j) {
    const int db = j & 1;
    __syncthreads();
    if (j + 1 < 32) stage(j + 1, db ^ 1);

    // S^T frags: rows pos = cf*16+quad*4+r, col qrow = l15
    f32x4 st[4][4];
#pragma unroll
    for (int cf = 0; cf < 4; ++cf) {
      int n = cf * 16 + l15;
      short8 kf0 = *(const short8*)(&Kt[db][n * 64 + ((quad ^ (n & 7)) << 3)]);
      short8 kf1 =
          *(const short8*)(&Kt[db][n * 64 + (((quad + 4) ^ (n & 7)) << 3)]);
#pragma unroll
      for (int mi = 0; mi < 4; ++mi) {
        f32x4 z = (f32x4){0.f, 0.f, 0.f, 0.f};
        z = __builtin_amdgcn_mfma_f32_16x16x32_bf16(kf0, qf[mi][0], z, 0, 0, 0);
        z = __builtin_amdgcn_mfma_f32_16x16x32_bf16(kf1, qf[mi][1], z, 0, 0, 0);
        st[mi][cf] = z;
      }
    }

    // P = exp2(S^T), pack, write to per-wave LDS [qrow][pos] (swizzled, b64)
#pragma unroll
    for (int mi = 0; mi < 4; ++mi)
#pragma unroll
      for (int cf = 0; cf < 4; ++cf) {
        float e0 = EXP2F(st[mi][cf][0]);
        float e1 = EXP2F(st[mi][cf][1]);
        float e2 = EXP2F(st[mi][cf][2]);
        float e3 = EXP2F(st[mi][cf][3]);
        uint2v dw;
        dw[0] = pkbf_trunc(e0, e1);
        dw[1] = pkbf_trunc(e2, e3);
        int row = mi * 16 + l15;
        int bb = 2 * cf + (quad >> 1);
        *(uint2v*)(&Pw[wv][row * 64 + ((bb ^ (l15 & 7)) << 3) +
                           (quad & 1) * 4]) = dw;
      }

    // read P as B-operand frags (rows qrow=l15, k=pos)
    short8 pa[4][2];
#pragma unroll
    for (int mi = 0; mi < 4; ++mi)
#pragma unroll
      for (int kc = 0; kc < 2; ++kc)
        pa[mi][kc] = *(const short8*)(&Pw[wv][(mi * 16 + l15) * 64 +
                                              (((kc * 4 + quad) ^ (l15 & 7))
                                               << 3)]);

    // O^T += V^T-frag * P ; l += ones * P
#pragma unroll
    for (int cf = 0; cf < 4; ++cf) {
      int f = cf * 16 + l15;
      short8 vb0 = *(const short8*)(&Vt[db][f * 64 + ((quad ^ (f & 7)) << 3)]);
      short8 vb1 =
          *(const short8*)(&Vt[db][f * 64 + (((quad + 4) ^ (f & 7)) << 3)]);
#pragma unroll
      for (int mi = 0; mi < 4; ++mi) {
        oat[mi][cf] = __builtin_amdgcn_mfma_f32_16x16x32_bf16(
            vb0, pa[mi][0], oat[mi][cf], 0, 0, 0);
        oat[mi][cf] = __builtin_amdgcn_mfma_f32_16x16x32_bf16(
            vb1, pa[mi][1], oat[mi][cf], 0, 0, 0);
      }
    }
#pragma unroll
    for (int mi = 0; mi < 4; ++mi) {
      loa[mi] = __builtin_amdgcn_mfma_f32_16x16x32_bf16(ones, pa[mi][0],
                                                        loa[mi], 0, 0, 0);
      loa[mi] = __builtin_amdgcn_mfma_f32_16x16x32_bf16(ones, pa[mi][1],
                                                        loa[mi], 0, 0, 0);
    }
  }

  // epilogue: normalize, transpose O^T -> [qrow][feat] via Pw, coalesced store
#pragma unroll
  for (int mi = 0; mi < 4; ++mi) {
    float inv = 1.0f / loa[mi][0];
#pragma unroll
    for (int cf = 0; cf < 4; ++cf) {
      uint2v dw;
      dw[0] = pkbf_rne(oat[mi][cf][0] * inv, oat[mi][cf][1] * inv);
      dw[1] = pkbf_rne(oat[mi][cf][2] * inv, oat[mi][cf][3] * inv);
      int row = mi * 16 + l15;
      int bb = 2 * cf + (quad >> 1);
      *(uint2v*)(&Pw[wv][row * 64 + ((bb ^ (l15 & 7)) << 3) + (quad & 1) * 4]) =
          dw;
    }
  }
  const int rr = lane >> 1, half = lane & 1;
#pragma unroll
  for (int rh = 0; rh < 2; ++rh) {
    int rrr = rr + rh * 32;
#pragma unroll
    for (int c = 0; c < 4; ++c) {
      short8 ov = *(const short8*)(&Pw[wv][rrr * 64 +
                                           (((half * 4 + c) ^ (rrr & 7)) << 3)]);
      int row = qt * 128 + wv * 64 + rrr;
      *(short8*)(&ob[(size_t)(b * SS + row) * DDIM + h * 64 + half * 32 +
                     c * 8]) = ov;
    }
  }
}

extern "C" void kernel_launch(void* const* d_in, const int* in_sizes, int n_in,
                              void* d_out, int out_size, void* d_ws,
                              size_t ws_size, hipStream_t stream) {
  const float* x = (const float*)d_in[0];
  const float* Wqkv = (const float*)d_in[1];
  const float* bqkv = (const float*)d_in[2];
  const float* Wproj = (const float*)d_in[3];
  const float* bproj = (const float*)d_in[4];
  float* out = (float*)d_out;

  ushort_t* xb = (ushort_t*)d_ws;
  ushort_t* wqb = xb + (size_t)4096 * 1024;
  ushort_t* wpb = wqb + (size_t)3072 * 1024;
  ushort_t* qkvb = wpb + (size_t)1024 * 1024;
  ushort_t* obuf = qkvb + (size_t)3 * BB * HH * SS * HEADK;

  const int n0 = 4096 * 1024 / 4, n1 = 3072 * 1024 / 4, n2 = 1024 * 1024 / 4;
  cvt3_kernel<<<(n0 + n1 + n2 + 255) / 256, 256, 0, stream>>>(
      x, xb, n0, Wqkv, wqb, n1, Wproj, wpb, n2);
  gemm_nt<0><<<dim3(3072 / 128, 4096 / 128), 256, 0, stream>>>(
      xb, wqb, bqkv, nullptr, qkvb, 4096, 3072, 1024);
  attn_kernel<<<dim3(512), 128, 0, stream>>>(qkvb, obuf);
  gemm_nt<1><<<dim3(1024 / 128, 4096 / 128), 256, 0, stream>>>(
      obuf, wpb, bproj, out, nullptr, 4096, 1024, 1024);
}

// Round 10
// 194.569 us; speedup vs baseline: 1.3627x; 1.0922x over previous
//
#include <hip/hip_runtime.h>
#include <cstdint>

typedef unsigned short ushort_t;
typedef short short8 __attribute__((ext_vector_type(8)));
typedef float f32x4 __attribute__((ext_vector_type(4)));
typedef float float4v __attribute__((ext_vector_type(4)));
typedef unsigned int uint2v __attribute__((ext_vector_type(2)));

#define DDIM 1024
#define HH 16
#define HEADK 64
#define BB 2
#define SS 2048

#if __has_builtin(__builtin_amdgcn_exp2f)
#define EXP2F(x) __builtin_amdgcn_exp2f(x)
#else
#define EXP2F(x) exp2f(x)
#endif

__device__ __forceinline__ ushort_t f2bf(float f) {
  union { float f; uint32_t u; } c; c.f = f;
  uint32_t u = c.u;
  u += 0x7fffu + ((u >> 16) & 1u);
  return (ushort_t)(u >> 16);
}

// truncation-pack two fp32 -> bf16x2 (1 v_perm). Bias cancels in l-normalization.
__device__ __forceinline__ uint32_t pkbf_trunc(float a, float b) {
  union { float f; uint32_t u; } ca, cb;
  ca.f = a; cb.f = b;
  return __builtin_amdgcn_perm(cb.u, ca.u, 0x07060302);
}

__device__ __forceinline__ uint32_t pkbf_rne(float a, float b) {
  return (uint32_t)f2bf(a) | ((uint32_t)f2bf(b) << 16);
}

__device__ __forceinline__ void glds16(const ushort_t* gp, ushort_t* lp) {
  __builtin_amdgcn_global_load_lds(
      (const __attribute__((address_space(1))) uint32_t*)gp,
      (__attribute__((address_space(3))) uint32_t*)lp, 16, 0, 0);
}

// ---------------- fp32 -> bf16 convert, 3 tensors in one launch ----------------
__global__ void cvt3_kernel(const float* __restrict__ s0, ushort_t* __restrict__ d0, int n0,
                            const float* __restrict__ s1, ushort_t* __restrict__ d1, int n1,
                            const float* __restrict__ s2, ushort_t* __restrict__ d2, int n2) {
  int i = blockIdx.x * blockDim.x + threadIdx.x;
  const float* src; ushort_t* dst; int k;
  if (i < n0) { src = s0; dst = d0; k = i; }
  else if (i < n0 + n1) { src = s1; dst = d1; k = i - n0; }
  else if (i < n0 + n1 + n2) { src = s2; dst = d2; k = i - n0 - n1; }
  else return;
  float4v v = ((const float4v*)src)[k];
  uint2v o; o[0] = pkbf_rne(v[0], v[1]); o[1] = pkbf_rne(v[2], v[3]);
  ((uint2v*)dst)[k] = o;
}

// ---------------- NT GEMM: C[M,N] = A[M,Kd] * Bm[N,Kd]^T + bias ----------------
// Tile TM x 128, BK=64, 4 waves (2x2 quadrants of (TM/2) x 64).
// MODE 0 (TM=128): scatter-write bf16 qkv: Q,K as [t][B][H][S][64] (Q pre-scaled
//   by 0.125*log2(e)); V region (tn0>=2048) transposed to [2][B][H][64][S] via
//   LDS transpose for coalesced stores.
// MODE 1 (TM=64): write fp32 C row-major (more blocks -> 2 waves/SIMD occupancy).
template <int MODE, int TM>
__global__ __launch_bounds__(256) void gemm_nt(
    const ushort_t* __restrict__ A, const ushort_t* __restrict__ Bm,
    const float* __restrict__ bias, float* __restrict__ Cout,
    ushort_t* __restrict__ Cbf, int M, int N, int Kd) {
  __shared__ ushort_t smem[128 * 64 * 2];  // As | Bs ; reused as 128x128 Ct (V epi)
  ushort_t* As = smem;
  ushort_t* Bs = smem + TM * 64;
  const int MI = TM / 32;  // m-frags per wave (4 or 2)
  const int tid = threadIdx.x;
  const int wv = tid >> 6, lane = tid & 63;
  const int l15 = lane & 15, quad = lane >> 4;
  const int wm = wv >> 1, wn = wv & 1;
  const int tm0 = blockIdx.y * TM, tn0 = blockIdx.x * 128;

  f32x4 acc[MI][4];
#pragma unroll
  for (int i = 0; i < MI; ++i)
#pragma unroll
    for (int j = 0; j < 4; ++j) acc[i][j] = (f32x4){0.f, 0.f, 0.f, 0.f};

  const int lrow = lane >> 3;
  const int gcb = (lane & 7) ^ lrow;
  const int ACI = TM / 32;  // A staging instrs per wave

  for (int k0 = 0; k0 < Kd; k0 += 64) {
#pragma unroll
    for (int c = 0; c < ACI; ++c) {
      int seg = wv * ACI + c;
      glds16(A + (size_t)(tm0 + seg * 8 + lrow) * Kd + k0 + gcb * 8,
             As + seg * 512);
    }
#pragma unroll
    for (int c = 0; c < 4; ++c) {
      int seg = wv * 4 + c;
      glds16(Bm + (size_t)(tn0 + seg * 8 + lrow) * Kd + k0 + gcb * 8,
             Bs + seg * 512);
    }
    __syncthreads();
#pragma unroll
    for (int kk = 0; kk < 64; kk += 32) {
      short8 af[MI], bfr[4];
#pragma unroll
      for (int i = 0; i < MI; ++i) {
        int r = wm * (TM / 2) + i * 16 + l15;
        int cb = (kk >> 3) + quad;
        af[i] = *(const short8*)(As + r * 64 + ((cb ^ (l15 & 7)) << 3));
      }
#pragma unroll
      for (int j = 0; j < 4; ++j) {
        int r = wn * 64 + j * 16 + l15;
        int cb = (kk >> 3) + quad;
        bfr[j] = *(const short8*)(Bs + r * 64 + ((cb ^ (l15 & 7)) << 3));
      }
#pragma unroll
      for (int i = 0; i < MI; ++i)
#pragma unroll
        for (int j = 0; j < 4; ++j)
          acc[i][j] = __builtin_amdgcn_mfma_f32_16x16x32_bf16(
              af[i], bfr[j], acc[i][j], 0, 0, 0);
    }
    __syncthreads();
  }

  if (MODE == 1) {
#pragma unroll
    for (int j = 0; j < 4; ++j) {
      int col = tn0 + wn * 64 + j * 16 + l15;
      float bv = bias[col];
#pragma unroll
      for (int i = 0; i < MI; ++i) {
        int row0 = tm0 + wm * (TM / 2) + i * 16 + quad * 4;
#pragma unroll
        for (int r = 0; r < 4; ++r)
          Cout[(size_t)(row0 + r) * N + col] = acc[i][j][r] + bv;
      }
    }
  } else {
    const int t = tn0 >> 10;  // uniform per block (128 | 1024)
    if (t < 2) {
      // Q/K: row-major [s][64] per head; 16-lane 32B runs, as before
#pragma unroll
      for (int j = 0; j < 4; ++j) {
        int col = tn0 + wn * 64 + j * 16 + l15;
        float bv = bias[col];
        int hh = (col >> 6) & 15, kk2 = col & 63;
#pragma unroll
        for (int i = 0; i < MI; ++i) {
          int row0 = tm0 + wm * (TM / 2) + i * 16 + quad * 4;
#pragma unroll
          for (int r = 0; r < 4; ++r) {
            int row = row0 + r;
            int b = row >> 11, s = row & 2047;
            float v = acc[i][j][r] + bv;
            if (t == 0) v *= 0.18033688f;  // 0.125*log2(e)
            size_t base =
                (((size_t)t * BB + b) * HH + hh) * ((size_t)SS * HEADK);
            Cbf[base + (size_t)s * HEADK + kk2] = f2bf(v);
          }
        }
      }
    } else {
      // V: transpose 128x128 tile through LDS -> coalesced [kk2][s] stores
      __syncthreads();  // frag reads of last K-iter complete; reuse smem
#pragma unroll
      for (int j = 0; j < 4; ++j) {
        int c = wn * 64 + j * 16 + l15;         // local col 0..127
        float bv = bias[tn0 + c];
#pragma unroll
        for (int i = 0; i < MI; ++i) {
          int row0 = wm * (TM / 2) + i * 16 + quad * 4;  // local row
          uint2v dw;
          dw[0] = pkbf_rne(acc[i][j][0] + bv, acc[i][j][1] + bv);
          dw[1] = pkbf_rne(acc[i][j][2] + bv, acc[i][j][3] + bv);
          int rb = row0 >> 3;
          *(uint2v*)(&smem[c * 128 + (((rb ^ (c & 15)) << 3) | (row0 & 7))]) =
              dw;
        }
      }
      __syncthreads();
      const int rb2 = lane & 15;  // 8-row block
      const int cg = lane >> 4;   // col subgroup
#pragma unroll
      for (int it = 0; it < 8; ++it) {
        int c = wv * 32 + it * 4 + cg;
        short8 vv = *(const short8*)(&smem[c * 128 + ((rb2 ^ (c & 15)) << 3)]);
        int gcol = tn0 + c;
        int hh = (gcol >> 6) & 15, kk2 = gcol & 63;
        int grow = tm0 + rb2 * 8;
        int b = grow >> 11, s = grow & 2047;
        size_t base = (((size_t)2 * BB + b) * HH + hh) * ((size_t)SS * HEADK);
        *(short8*)(&Cbf[base + (size_t)kk2 * SS + s]) = vv;
      }
    }
  }
}

// ---------------- flash attention (round-3 proven structure) ----------------
// grid (S/64, H, B), 128 threads (2 waves x 32 Q-rows), KV tile 64 double-buffered.
// S^T = mfma(K,Q): each lane owns one Q-row's scores; no max-tracking (scores
// bounded in exp2 domain); l via ones-MFMA; P->A-layout via per-wave LDS.
__global__ __launch_bounds__(128, 2) void attn_kernel(
    const ushort_t* __restrict__ qkv, ushort_t* __restrict__ ob) {
  __shared__ ushort_t Kt[2][64 * 64];   // [pos][feat], XOR-swizzled 16B blocks
  __shared__ ushort_t Vt[2][64 * 64];   // [feat][pos], XOR-swizzled 16B blocks
  __shared__ ushort_t Pw[2][32 * 64];   // per-wave P [qrow][pos], swizzled

  const int qt = blockIdx.x, h = blockIdx.y, b = blockIdx.z;
  const int tid = threadIdx.x;
  const int wv = tid >> 6, lane = tid & 63;
  const int l15 = lane & 15, quad = lane >> 4;

  const size_t hstride = (size_t)SS * HEADK;
  const ushort_t* Qg = qkv + ((size_t)(0 * BB + b) * HH + h) * hstride;
  const ushort_t* Kg = qkv + ((size_t)(1 * BB + b) * HH + h) * hstride;
  const ushort_t* Vg = qkv + ((size_t)(2 * BB + b) * HH + h) * hstride; // [64][2048]

  short8 qf[2][2];
#pragma unroll
  for (int mi = 0; mi < 2; ++mi)
#pragma unroll
    for (int kc = 0; kc < 2; ++kc)
      qf[mi][kc] = *(const short8*)(
          Qg + (size_t)(qt * 64 + wv * 32 + mi * 16 + l15) * 64 + kc * 32 +
          quad * 8);

  const short ONE = (short)0x3F80;  // bf16 1.0
  short8 ones = {ONE, ONE, ONE, ONE, ONE, ONE, ONE, ONE};

  f32x4 oat[2][4];  // O^T: rows feat=cf*16+quad*4+r, col qrow=l15
  f32x4 loa[2];     // l: col qrow=l15
#pragma unroll
  for (int mi = 0; mi < 2; ++mi) {
    loa[mi] = (f32x4){0.f, 0.f, 0.f, 0.f};
#pragma unroll
    for (int c = 0; c < 4; ++c) oat[mi][c] = (f32x4){0.f, 0.f, 0.f, 0.f};
  }

  const int lrow = lane >> 3, gcb = (lane & 7) ^ lrow;

  auto stage = [&](int jj, int db) {
#pragma unroll
    for (int c = 0; c < 4; ++c) {
      int seg = wv * 4 + c;
      glds16(Kg + (size_t)(jj * 64 + seg * 8 + lrow) * 64 + gcb * 8,
             &Kt[db][seg * 512]);
    }
#pragma unroll
    for (int c = 0; c < 4; ++c) {
      int seg = wv * 4 + c;
      glds16(Vg + (size_t)(seg * 8 + lrow) * SS + jj * 64 + gcb * 8,
             &Vt[db][seg * 512]);
    }
  };

  stage(0, 0);

  for (int j = 0; j < 32; ++j) {
    const int db = j & 1;
    __syncthreads();
    if (j + 1 < 32) stage(j + 1, db ^ 1);

    f32x4 st[2][4];
#pragma unroll
    for (int cf = 0; cf < 4; ++cf) {
      int n = cf * 16 + l15;
      short8 kf0 = *(const short8*)(&Kt[db][n * 64 + ((quad ^ (n & 7)) << 3)]);
      short8 kf1 =
          *(const short8*)(&Kt[db][n * 64 + (((quad + 4) ^ (n & 7)) << 3)]);
#pragma unroll
      for (int mi = 0; mi < 2; ++mi) {
        f32x4 z = (f32x4){0.f, 0.f, 0.f, 0.f};
        z = __builtin_amdgcn_mfma_f32_16x16x32_bf16(kf0, qf[mi][0], z, 0, 0, 0);
        z = __builtin_amdgcn_mfma_f32_16x16x32_bf16(kf1, qf[mi][1], z, 0, 0, 0);
        st[mi][cf] = z;
      }
    }

#pragma unroll
    for (int mi = 0; mi < 2; ++mi)
#pragma unroll
      for (int cf = 0; cf < 4; ++cf) {
        float e0 = EXP2F(st[mi][cf][0]);
        float e1 = EXP2F(st[mi][cf][1]);
        float e2 = EXP2F(st[mi][cf][2]);
        float e3 = EXP2F(st[mi][cf][3]);
        uint2v dw;
        dw[0] = pkbf_trunc(e0, e1);
        dw[1] = pkbf_trunc(e2, e3);
        int row = mi * 16 + l15;
        int bb = 2 * cf + (quad >> 1);
        *(uint2v*)(&Pw[wv][row * 64 + ((bb ^ (l15 & 7)) << 3) +
                           (quad & 1) * 4]) = dw;
      }

    short8 pa[2][2];
#pragma unroll
    for (int mi = 0; mi < 2; ++mi)
#pragma unroll
      for (int kc = 0; kc < 2; ++kc)
        pa[mi][kc] = *(const short8*)(&Pw[wv][(mi * 16 + l15) * 64 +
                                              (((kc * 4 + quad) ^ (l15 & 7))
                                               << 3)]);

#pragma unroll
    for (int cf = 0; cf < 4; ++cf) {
      int f = cf * 16 + l15;
      short8 vb0 = *(const short8*)(&Vt[db][f * 64 + ((quad ^ (f & 7)) << 3)]);
      short8 vb1 =
          *(const short8*)(&Vt[db][f * 64 + (((quad + 4) ^ (f & 7)) << 3)]);
#pragma unroll
      for (int mi = 0; mi < 2; ++mi) {
        oat[mi][cf] = __builtin_amdgcn_mfma_f32_16x16x32_bf16(
            vb0, pa[mi][0], oat[mi][cf], 0, 0, 0);
        oat[mi][cf] = __builtin_amdgcn_mfma_f32_16x16x32_bf16(
            vb1, pa[mi][1], oat[mi][cf], 0, 0, 0);
      }
    }
#pragma unroll
    for (int mi = 0; mi < 2; ++mi) {
      loa[mi] = __builtin_amdgcn_mfma_f32_16x16x32_bf16(ones, pa[mi][0],
                                                        loa[mi], 0, 0, 0);
      loa[mi] = __builtin_amdgcn_mfma_f32_16x16x32_bf16(ones, pa[mi][1],
                                                        loa[mi], 0, 0, 0);
    }
  }

#pragma unroll
  for (int mi = 0; mi < 2; ++mi) {
    float inv = 1.0f / loa[mi][0];
#pragma unroll
    for (int cf = 0; cf < 4; ++cf) {
      uint2v dw;
      dw[0] = pkbf_rne(oat[mi][cf][0] * inv, oat[mi][cf][1] * inv);
      dw[1] = pkbf_rne(oat[mi][cf][2] * inv, oat[mi][cf][3] * inv);
      int row = mi * 16 + l15;
      int bb = 2 * cf + (quad >> 1);
      *(uint2v*)(&Pw[wv][row * 64 + ((bb ^ (l15 & 7)) << 3) + (quad & 1) * 4]) =
          dw;
    }
  }
  const int rr = lane >> 1, half = lane & 1;
#pragma unroll
  for (int c = 0; c < 4; ++c) {
    short8 ov = *(const short8*)(&Pw[wv][rr * 64 +
                                         (((half * 4 + c) ^ (rr & 7)) << 3)]);
    int row = qt * 64 + wv * 32 + rr;
    *(short8*)(&ob[(size_t)(b * SS + row) * DDIM + h * 64 + half * 32 +
                   c * 8]) = ov;
  }
}

extern "C" void kernel_launch(void* const* d_in, const int* in_sizes, int n_in,
                              void* d_out, int out_size, void* d_ws,
                              size_t ws_size, hipStream_t stream) {
  const float* x = (const float*)d_in[0];
  const float* Wqkv = (const float*)d_in[1];
  const float* bqkv = (const float*)d_in[2];
  const float* Wproj = (const float*)d_in[3];
  const float* bproj = (const float*)d_in[4];
  float* out = (float*)d_out;

  ushort_t* xb = (ushort_t*)d_ws;
  ushort_t* wqb = xb + (size_t)4096 * 1024;
  ushort_t* wpb = wqb + (size_t)3072 * 1024;
  ushort_t* qkvb = wpb + (size_t)1024 * 1024;
  ushort_t* obuf = qkvb + (size_t)3 * BB * HH * SS * HEADK;

  const int n0 = 4096 * 1024 / 4, n1 = 3072 * 1024 / 4, n2 = 1024 * 1024 / 4;
  cvt3_kernel<<<(n0 + n1 + n2 + 255) / 256, 256, 0, stream>>>(
      x, xb, n0, Wqkv, wqb, n1, Wproj, wpb, n2);
  gemm_nt<0, 128><<<dim3(3072 / 128, 4096 / 128), 256, 0, stream>>>(
      xb, wqb, bqkv, nullptr, qkvb, 4096, 3072, 1024);
  attn_kernel<<<dim3(SS / 64, HH, BB), 128, 0, stream>>>(qkvb, obuf);
  gemm_nt<1, 64><<<dim3(1024 / 128, 4096 / 64), 256, 0, stream>>>(
      obuf, wpb, bproj, out, nullptr, 4096, 1024, 1024);
}

// Round 11
// 193.115 us; speedup vs baseline: 1.3730x; 1.0075x over previous
//
#include <hip/hip_runtime.h>
#include <cstdint>

typedef unsigned short ushort_t;
typedef short short8 __attribute__((ext_vector_type(8)));
typedef float f32x4 __attribute__((ext_vector_type(4)));
typedef float float4v __attribute__((ext_vector_type(4)));
typedef unsigned int uint2v __attribute__((ext_vector_type(2)));

#define DDIM 1024
#define HH 16
#define HEADK 64
#define BB 2
#define SS 2048

#if __has_builtin(__builtin_amdgcn_exp2f)
#define EXP2F(x) __builtin_amdgcn_exp2f(x)
#else
#define EXP2F(x) exp2f(x)
#endif

__device__ __forceinline__ ushort_t f2bf(float f) {
  union { float f; uint32_t u; } c; c.f = f;
  uint32_t u = c.u;
  u += 0x7fffu + ((u >> 16) & 1u);
  return (ushort_t)(u >> 16);
}

// truncation-pack two fp32 -> bf16x2 (1 v_perm). Bias cancels in l-normalization.
__device__ __forceinline__ uint32_t pkbf_trunc(float a, float b) {
  union { float f; uint32_t u; } ca, cb;
  ca.f = a; cb.f = b;
  return __builtin_amdgcn_perm(cb.u, ca.u, 0x07060302);
}

__device__ __forceinline__ uint32_t pkbf_rne(float a, float b) {
  return (uint32_t)f2bf(a) | ((uint32_t)f2bf(b) << 16);
}

__device__ __forceinline__ void glds16(const ushort_t* gp, ushort_t* lp) {
  __builtin_amdgcn_global_load_lds(
      (const __attribute__((address_space(1))) uint32_t*)gp,
      (__attribute__((address_space(3))) uint32_t*)lp, 16, 0, 0);
}

// ---------------- fp32 -> bf16 convert, 3 tensors in one launch ----------------
__global__ void cvt3_kernel(const float* __restrict__ s0, ushort_t* __restrict__ d0, int n0,
                            const float* __restrict__ s1, ushort_t* __restrict__ d1, int n1,
                            const float* __restrict__ s2, ushort_t* __restrict__ d2, int n2) {
  int i = blockIdx.x * blockDim.x + threadIdx.x;
  const float* src; ushort_t* dst; int k;
  if (i < n0) { src = s0; dst = d0; k = i; }
  else if (i < n0 + n1) { src = s1; dst = d1; k = i - n0; }
  else if (i < n0 + n1 + n2) { src = s2; dst = d2; k = i - n0 - n1; }
  else return;
  float4v v = ((const float4v*)src)[k];
  uint2v o; o[0] = pkbf_rne(v[0], v[1]); o[1] = pkbf_rne(v[2], v[3]);
  ((uint2v*)dst)[k] = o;
}

// ---------------- NT GEMM: C[M,N] = A[M,Kd] * Bm[N,Kd]^T + bias ----------------
// Tile TM x 128, BK=64, 4 waves (2x2 quadrants of (TM/2) x 64).
// MODE 0 (TM=128): scatter-write bf16 qkv: Q,K as [t][B][H][S][64] (Q pre-scaled
//   by 0.125*log2(e)); V region (tn0>=2048) transposed to [2][B][H][64][S] via
//   LDS transpose for coalesced stores.
// MODE 1 (TM=64): write fp32 C row-major (more blocks -> 2 waves/SIMD occupancy).
template <int MODE, int TM>
__global__ __launch_bounds__(256) void gemm_nt(
    const ushort_t* __restrict__ A, const ushort_t* __restrict__ Bm,
    const float* __restrict__ bias, float* __restrict__ Cout,
    ushort_t* __restrict__ Cbf, int M, int N, int Kd) {
  __shared__ ushort_t smem[128 * 64 * 2];  // As | Bs ; reused as 128x128 Ct (V epi)
  ushort_t* As = smem;
  ushort_t* Bs = smem + TM * 64;
  const int MI = TM / 32;  // m-frags per wave (4 or 2)
  const int tid = threadIdx.x;
  const int wv = tid >> 6, lane = tid & 63;
  const int l15 = lane & 15, quad = lane >> 4;
  const int wm = wv >> 1, wn = wv & 1;
  const int tm0 = blockIdx.y * TM, tn0 = blockIdx.x * 128;

  f32x4 acc[MI][4];
#pragma unroll
  for (int i = 0; i < MI; ++i)
#pragma unroll
    for (int j = 0; j < 4; ++j) acc[i][j] = (f32x4){0.f, 0.f, 0.f, 0.f};

  const int lrow = lane >> 3;
  const int gcb = (lane & 7) ^ lrow;
  const int ACI = TM / 32;  // A staging instrs per wave

  for (int k0 = 0; k0 < Kd; k0 += 64) {
#pragma unroll
    for (int c = 0; c < ACI; ++c) {
      int seg = wv * ACI + c;
      glds16(A + (size_t)(tm0 + seg * 8 + lrow) * Kd + k0 + gcb * 8,
             As + seg * 512);
    }
#pragma unroll
    for (int c = 0; c < 4; ++c) {
      int seg = wv * 4 + c;
      glds16(Bm + (size_t)(tn0 + seg * 8 + lrow) * Kd + k0 + gcb * 8,
             Bs + seg * 512);
    }
    __syncthreads();
#pragma unroll
    for (int kk = 0; kk < 64; kk += 32) {
      short8 af[MI], bfr[4];
#pragma unroll
      for (int i = 0; i < MI; ++i) {
        int r = wm * (TM / 2) + i * 16 + l15;
        int cb = (kk >> 3) + quad;
        af[i] = *(const short8*)(As + r * 64 + ((cb ^ (l15 & 7)) << 3));
      }
#pragma unroll
      for (int j = 0; j < 4; ++j) {
        int r = wn * 64 + j * 16 + l15;
        int cb = (kk >> 3) + quad;
        bfr[j] = *(const short8*)(Bs + r * 64 + ((cb ^ (l15 & 7)) << 3));
      }
#pragma unroll
      for (int i = 0; i < MI; ++i)
#pragma unroll
        for (int j = 0; j < 4; ++j)
          acc[i][j] = __builtin_amdgcn_mfma_f32_16x16x32_bf16(
              af[i], bfr[j], acc[i][j], 0, 0, 0);
    }
    __syncthreads();
  }

  if (MODE == 1) {
#pragma unroll
    for (int j = 0; j < 4; ++j) {
      int col = tn0 + wn * 64 + j * 16 + l15;
      float bv = bias[col];
#pragma unroll
      for (int i = 0; i < MI; ++i) {
        int row0 = tm0 + wm * (TM / 2) + i * 16 + quad * 4;
#pragma unroll
        for (int r = 0; r < 4; ++r)
          Cout[(size_t)(row0 + r) * N + col] = acc[i][j][r] + bv;
      }
    }
  } else {
    const int t = tn0 >> 10;  // uniform per block (128 | 1024)
    if (t < 2) {
      // Q/K: row-major [s][64] per head; 16-lane 32B runs
#pragma unroll
      for (int j = 0; j < 4; ++j) {
        int col = tn0 + wn * 64 + j * 16 + l15;
        float bv = bias[col];
        int hh = (col >> 6) & 15, kk2 = col & 63;
#pragma unroll
        for (int i = 0; i < MI; ++i) {
          int row0 = tm0 + wm * (TM / 2) + i * 16 + quad * 4;
#pragma unroll
          for (int r = 0; r < 4; ++r) {
            int row = row0 + r;
            int b = row >> 11, s = row & 2047;
            float v = acc[i][j][r] + bv;
            if (t == 0) v *= 0.18033688f;  // 0.125*log2(e)
            size_t base =
                (((size_t)t * BB + b) * HH + hh) * ((size_t)SS * HEADK);
            Cbf[base + (size_t)s * HEADK + kk2] = f2bf(v);
          }
        }
      }
    } else {
      // V: transpose 128x128 tile through LDS -> coalesced [kk2][s] stores
      __syncthreads();  // frag reads of last K-iter complete; reuse smem
#pragma unroll
      for (int j = 0; j < 4; ++j) {
        int c = wn * 64 + j * 16 + l15;         // local col 0..127
        float bv = bias[tn0 + c];
#pragma unroll
        for (int i = 0; i < MI; ++i) {
          int row0 = wm * (TM / 2) + i * 16 + quad * 4;  // local row
          uint2v dw;
          dw[0] = pkbf_rne(acc[i][j][0] + bv, acc[i][j][1] + bv);
          dw[1] = pkbf_rne(acc[i][j][2] + bv, acc[i][j][3] + bv);
          int rb = row0 >> 3;
          *(uint2v*)(&smem[c * 128 + (((rb ^ (c & 15)) << 3) | (row0 & 7))]) =
              dw;
        }
      }
      __syncthreads();
      const int rb2 = lane & 15;  // 8-row block
      const int cg = lane >> 4;   // col subgroup
#pragma unroll
      for (int it = 0; it < 8; ++it) {
        int c = wv * 32 + it * 4 + cg;
        short8 vv = *(const short8*)(&smem[c * 128 + ((rb2 ^ (c & 15)) << 3)]);
        int gcol = tn0 + c;
        int hh = (gcol >> 6) & 15, kk2 = gcol & 63;
        int grow = tm0 + rb2 * 8;
        int b = grow >> 11, s = grow & 2047;
        size_t base = (((size_t)2 * BB + b) * HH + hh) * ((size_t)SS * HEADK);
        *(short8*)(&Cbf[base + (size_t)kk2 * SS + s]) = vv;
      }
    }
  }
}

// ---------------- flash attention ----------------
// grid (S/128, H, B), 256 threads = 4 waves x 32 Q-rows sharing one staged KV
// tile (halves staging DMA, L2 re-reads, and barriers per q-row vs 2-wave
// blocks). KV tile 64 double-buffered via glds16; S^T = mfma(K,Q) so each lane
// owns one Q-row's scores; no max-tracking (exp2-domain scores bounded); l via
// ones-MFMA; P->A-layout via per-wave LDS slab.
__global__ __launch_bounds__(256, 2) void attn_kernel(
    const ushort_t* __restrict__ qkv, ushort_t* __restrict__ ob) {
  __shared__ ushort_t Kt[2][64 * 64];   // [pos][feat], XOR-swizzled 16B blocks
  __shared__ ushort_t Vt[2][64 * 64];   // [feat][pos], XOR-swizzled 16B blocks
  __shared__ ushort_t Pw[4][32 * 64];   // per-wave P [qrow][pos], swizzled

  const int qt = blockIdx.x, h = blockIdx.y, b = blockIdx.z;
  const int tid = threadIdx.x;
  const int wv = tid >> 6, lane = tid & 63;
  const int l15 = lane & 15, quad = lane >> 4;

  const size_t hstride = (size_t)SS * HEADK;
  const ushort_t* Qg = qkv + ((size_t)(0 * BB + b) * HH + h) * hstride;
  const ushort_t* Kg = qkv + ((size_t)(1 * BB + b) * HH + h) * hstride;
  const ushort_t* Vg = qkv + ((size_t)(2 * BB + b) * HH + h) * hstride; // [64][2048]

  short8 qf[2][2];
#pragma unroll
  for (int mi = 0; mi < 2; ++mi)
#pragma unroll
    for (int kc = 0; kc < 2; ++kc)
      qf[mi][kc] = *(const short8*)(
          Qg + (size_t)(qt * 128 + wv * 32 + mi * 16 + l15) * 64 + kc * 32 +
          quad * 8);

  const short ONE = (short)0x3F80;  // bf16 1.0
  short8 ones = {ONE, ONE, ONE, ONE, ONE, ONE, ONE, ONE};

  f32x4 oat[2][4];  // O^T: rows feat=cf*16+quad*4+r, col qrow=l15
  f32x4 loa[2];     // l: col qrow=l15
#pragma unroll
  for (int mi = 0; mi < 2; ++mi) {
    loa[mi] = (f32x4){0.f, 0.f, 0.f, 0.f};
#pragma unroll
    for (int c = 0; c < 4; ++c) oat[mi][c] = (f32x4){0.f, 0.f, 0.f, 0.f};
  }

  const int lrow = lane >> 3, gcb = (lane & 7) ^ lrow;

  auto stage = [&](int jj, int db) {
#pragma unroll
    for (int c = 0; c < 2; ++c) {
      int seg = wv * 2 + c;  // 0..7 over 4 waves
      glds16(Kg + (size_t)(jj * 64 + seg * 8 + lrow) * 64 + gcb * 8,
             &Kt[db][seg * 512]);
    }
#pragma unroll
    for (int c = 0; c < 2; ++c) {
      int seg = wv * 2 + c;
      glds16(Vg + (size_t)(seg * 8 + lrow) * SS + jj * 64 + gcb * 8,
             &Vt[db][seg * 512]);
    }
  };

  stage(0, 0);

  for (int j = 0; j < 32; ++j) {
    const int db = j & 1;
    __syncthreads();
    if (j + 1 < 32) stage(j + 1, db ^ 1);

    f32x4 st[2][4];
#pragma unroll
    for (int cf = 0; cf < 4; ++cf) {
      int n = cf * 16 + l15;
      short8 kf0 = *(const short8*)(&Kt[db][n * 64 + ((quad ^ (n & 7)) << 3)]);
      short8 kf1 =
          *(const short8*)(&Kt[db][n * 64 + (((quad + 4) ^ (n & 7)) << 3)]);
#pragma unroll
      for (int mi = 0; mi < 2; ++mi) {
        f32x4 z = (f32x4){0.f, 0.f, 0.f, 0.f};
        z = __builtin_amdgcn_mfma_f32_16x16x32_bf16(kf0, qf[mi][0], z, 0, 0, 0);
        z = __builtin_amdgcn_mfma_f32_16x16x32_bf16(kf1, qf[mi][1], z, 0, 0, 0);
        st[mi][cf] = z;
      }
    }

#pragma unroll
    for (int mi = 0; mi < 2; ++mi)
#pragma unroll
      for (int cf = 0; cf < 4; ++cf) {
        float e0 = EXP2F(st[mi][cf][0]);
        float e1 = EXP2F(st[mi][cf][1]);
        float e2 = EXP2F(st[mi][cf][2]);
        float e3 = EXP2F(st[mi][cf][3]);
        uint2v dw;
        dw[0] = pkbf_trunc(e0, e1);
        dw[1] = pkbf_trunc(e2, e3);
        int row = mi * 16 + l15;
        int bb = 2 * cf + (quad >> 1);
        *(uint2v*)(&Pw[wv][row * 64 + ((bb ^ (l15 & 7)) << 3) +
                           (quad & 1) * 4]) = dw;
      }

    short8 pa[2][2];
#pragma unroll
    for (int mi = 0; mi < 2; ++mi)
#pragma unroll
      for (int kc = 0; kc < 2; ++kc)
        pa[mi][kc] = *(const short8*)(&Pw[wv][(mi * 16 + l15) * 64 +
                                              (((kc * 4 + quad) ^ (l15 & 7))
                                               << 3)]);

#pragma unroll
    for (int cf = 0; cf < 4; ++cf) {
      int f = cf * 16 + l15;
      short8 vb0 = *(const short8*)(&Vt[db][f * 64 + ((quad ^ (f & 7)) << 3)]);
      short8 vb1 =
          *(const short8*)(&Vt[db][f * 64 + (((quad + 4) ^ (f & 7)) << 3)]);
#pragma unroll
      for (int mi = 0; mi < 2; ++mi) {
        oat[mi][cf] = __builtin_amdgcn_mfma_f32_16x16x32_bf16(
            vb0, pa[mi][0], oat[mi][cf], 0, 0, 0);
        oat[mi][cf] = __builtin_amdgcn_mfma_f32_16x16x32_bf16(
            vb1, pa[mi][1], oat[mi][cf], 0, 0, 0);
      }
    }
#pragma unroll
    for (int mi = 0; mi < 2; ++mi) {
      loa[mi] = __builtin_amdgcn_mfma_f32_16x16x32_bf16(ones, pa[mi][0],
                                                        loa[mi], 0, 0, 0);
      loa[mi] = __builtin_amdgcn_mfma_f32_16x16x32_bf16(ones, pa[mi][1],
                                                        loa[mi], 0, 0, 0);
    }
  }

#pragma unroll
  for (int mi = 0; mi < 2; ++mi) {
    float inv = 1.0f / loa[mi][0];
#pragma unroll
    for (int cf = 0; cf < 4; ++cf) {
      uint2v dw;
      dw[0] = pkbf_rne(oat[mi][cf][0] * inv, oat[mi][cf][1] * inv);
      dw[1] = pkbf_rne(oat[mi][cf][2] * inv, oat[mi][cf][3] * inv);
      int row = mi * 16 + l15;
      int bb = 2 * cf + (quad >> 1);
      *(uint2v*)(&Pw[wv][row * 64 + ((bb ^ (l15 & 7)) << 3) + (quad & 1) * 4]) =
          dw;
    }
  }
  const int rr = lane >> 1, half = lane & 1;
#pragma unroll
  for (int c = 0; c < 4; ++c) {
    short8 ov = *(const short8*)(&Pw[wv][rr * 64 +
                                         (((half * 4 + c) ^ (rr & 7)) << 3)]);
    int row = qt * 128 + wv * 32 + rr;
    *(short8*)(&ob[(size_t)(b * SS + row) * DDIM + h * 64 + half * 32 +
                   c * 8]) = ov;
  }
}

extern "C" void kernel_launch(void* const* d_in, const int* in_sizes, int n_in,
                              void* d_out, int out_size, void* d_ws,
                              size_t ws_size, hipStream_t stream) {
  const float* x = (const float*)d_in[0];
  const float* Wqkv = (const float*)d_in[1];
  const float* bqkv = (const float*)d_in[2];
  const float* Wproj = (const float*)d_in[3];
  const float* bproj = (const float*)d_in[4];
  float* out = (float*)d_out;

  ushort_t* xb = (ushort_t*)d_ws;
  ushort_t* wqb = xb + (size_t)4096 * 1024;
  ushort_t* wpb = wqb + (size_t)3072 * 1024;
  ushort_t* qkvb = wpb + (size_t)1024 * 1024;
  ushort_t* obuf = qkvb + (size_t)3 * BB * HH * SS * HEADK;

  const int n0 = 4096 * 1024 / 4, n1 = 3072 * 1024 / 4, n2 = 1024 * 1024 / 4;
  cvt3_kernel<<<(n0 + n1 + n2 + 255) / 256, 256, 0, stream>>>(
      x, xb, n0, Wqkv, wqb, n1, Wproj, wpb, n2);
  gemm_nt<0, 128><<<dim3(3072 / 128, 4096 / 128), 256, 0, stream>>>(
      xb, wqb, bqkv, nullptr, qkvb, 4096, 3072, 1024);
  attn_kernel<<<dim3(SS / 128, HH, BB), 256, 0, stream>>>(qkvb, obuf);
  gemm_nt<1, 64><<<dim3(1024 / 128, 4096 / 64), 256, 0, stream>>>(
      obuf, wpb, bproj, out, nullptr, 4096, 1024, 1024);
}

// Round 13
// 192.821 us; speedup vs baseline: 1.3751x; 1.0015x over previous
//
#include <hip/hip_runtime.h>
#include <cstdint>

typedef unsigned short ushort_t;
typedef short short8 __attribute__((ext_vector_type(8)));
typedef float f32x4 __attribute__((ext_vector_type(4)));
typedef float float4v __attribute__((ext_vector_type(4)));
typedef unsigned int uint2v __attribute__((ext_vector_type(2)));

#define DDIM 1024
#define HH 16
#define HEADK 64
#define BB 2
#define SS 2048

#if __has_builtin(__builtin_amdgcn_exp2f)
#define EXP2F(x) __builtin_amdgcn_exp2f(x)
#else
#define EXP2F(x) exp2f(x)
#endif

__device__ __forceinline__ ushort_t f2bf(float f) {
  union { float f; uint32_t u; } c; c.f = f;
  uint32_t u = c.u;
  u += 0x7fffu + ((u >> 16) & 1u);
  return (ushort_t)(u >> 16);
}

// truncation-pack two fp32 -> bf16x2 (1 v_perm). Bias cancels in l-normalization.
__device__ __forceinline__ uint32_t pkbf_trunc(float a, float b) {
  union { float f; uint32_t u; } ca, cb;
  ca.f = a; cb.f = b;
  return __builtin_amdgcn_perm(cb.u, ca.u, 0x07060302);
}

__device__ __forceinline__ uint32_t pkbf_rne(float a, float b) {
  return (uint32_t)f2bf(a) | ((uint32_t)f2bf(b) << 16);
}

__device__ __forceinline__ float bfhi2f(uint32_t u) {  // high half
  union { uint32_t u; float f; } c; c.u = u & 0xffff0000u; return c.f;
}
__device__ __forceinline__ float bflo2f(uint32_t u) {  // low half
  union { uint32_t u; float f; } c; c.u = u << 16; return c.f;
}

__device__ __forceinline__ void glds16(const ushort_t* gp, ushort_t* lp) {
  __builtin_amdgcn_global_load_lds(
      (const __attribute__((address_space(1))) uint32_t*)gp,
      (__attribute__((address_space(3))) uint32_t*)lp, 16, 0, 0);
}

// ---------------- fp32 -> bf16 convert, 3 tensors in one launch ----------------
__global__ void cvt3_kernel(const float* __restrict__ s0, ushort_t* __restrict__ d0, int n0,
                            const float* __restrict__ s1, ushort_t* __restrict__ d1, int n1,
                            const float* __restrict__ s2, ushort_t* __restrict__ d2, int n2) {
  int i = blockIdx.x * blockDim.x + threadIdx.x;
  const float* src; ushort_t* dst; int k;
  if (i < n0) { src = s0; dst = d0; k = i; }
  else if (i < n0 + n1) { src = s1; dst = d1; k = i - n0; }
  else if (i < n0 + n1 + n2) { src = s2; dst = d2; k = i - n0 - n1; }
  else return;
  float4v v = ((const float4v*)src)[k];
  uint2v o; o[0] = pkbf_rne(v[0], v[1]); o[1] = pkbf_rne(v[2], v[3]);
  ((uint2v*)dst)[k] = o;
}

// ---------------- NT GEMM: C[M,N] = A[M,Kd] * Bm[N,Kd]^T + bias ----------------
// (unchanged from round 11)
template <int MODE, int TM>
__global__ __launch_bounds__(256) void gemm_nt(
    const ushort_t* __restrict__ A, const ushort_t* __restrict__ Bm,
    const float* __restrict__ bias, float* __restrict__ Cout,
    ushort_t* __restrict__ Cbf, int M, int N, int Kd) {
  __shared__ ushort_t smem[128 * 64 * 2];
  ushort_t* As = smem;
  ushort_t* Bs = smem + TM * 64;
  const int MI = TM / 32;
  const int tid = threadIdx.x;
  const int wv = tid >> 6, lane = tid & 63;
  const int l15 = lane & 15, quad = lane >> 4;
  const int wm = wv >> 1, wn = wv & 1;
  const int tm0 = blockIdx.y * TM, tn0 = blockIdx.x * 128;

  f32x4 acc[MI][4];
#pragma unroll
  for (int i = 0; i < MI; ++i)
#pragma unroll
    for (int j = 0; j < 4; ++j) acc[i][j] = (f32x4){0.f, 0.f, 0.f, 0.f};

  const int lrow = lane >> 3;
  const int gcb = (lane & 7) ^ lrow;
  const int ACI = TM / 32;

  for (int k0 = 0; k0 < Kd; k0 += 64) {
#pragma unroll
    for (int c = 0; c < ACI; ++c) {
      int seg = wv * ACI + c;
      glds16(A + (size_t)(tm0 + seg * 8 + lrow) * Kd + k0 + gcb * 8,
             As + seg * 512);
    }
#pragma unroll
    for (int c = 0; c < 4; ++c) {
      int seg = wv * 4 + c;
      glds16(Bm + (size_t)(tn0 + seg * 8 + lrow) * Kd + k0 + gcb * 8,
             Bs + seg * 512);
    }
    __syncthreads();
#pragma unroll
    for (int kk = 0; kk < 64; kk += 32) {
      short8 af[MI], bfr[4];
#pragma unroll
      for (int i = 0; i < MI; ++i) {
        int r = wm * (TM / 2) + i * 16 + l15;
        int cb = (kk >> 3) + quad;
        af[i] = *(const short8*)(As + r * 64 + ((cb ^ (l15 & 7)) << 3));
      }
#pragma unroll
      for (int j = 0; j < 4; ++j) {
        int r = wn * 64 + j * 16 + l15;
        int cb = (kk >> 3) + quad;
        bfr[j] = *(const short8*)(Bs + r * 64 + ((cb ^ (l15 & 7)) << 3));
      }
#pragma unroll
      for (int i = 0; i < MI; ++i)
#pragma unroll
        for (int j = 0; j < 4; ++j)
          acc[i][j] = __builtin_amdgcn_mfma_f32_16x16x32_bf16(
              af[i], bfr[j], acc[i][j], 0, 0, 0);
    }
    __syncthreads();
  }

  if (MODE == 1) {
#pragma unroll
    for (int j = 0; j < 4; ++j) {
      int col = tn0 + wn * 64 + j * 16 + l15;
      float bv = bias[col];
#pragma unroll
      for (int i = 0; i < MI; ++i) {
        int row0 = tm0 + wm * (TM / 2) + i * 16 + quad * 4;
#pragma unroll
        for (int r = 0; r < 4; ++r)
          Cout[(size_t)(row0 + r) * N + col] = acc[i][j][r] + bv;
      }
    }
  } else {
    const int t = tn0 >> 10;
    if (t < 2) {
#pragma unroll
      for (int j = 0; j < 4; ++j) {
        int col = tn0 + wn * 64 + j * 16 + l15;
        float bv = bias[col];
        int hh = (col >> 6) & 15, kk2 = col & 63;
#pragma unroll
        for (int i = 0; i < MI; ++i) {
          int row0 = tm0 + wm * (TM / 2) + i * 16 + quad * 4;
#pragma unroll
          for (int r = 0; r < 4; ++r) {
            int row = row0 + r;
            int b = row >> 11, s = row & 2047;
            float v = acc[i][j][r] + bv;
            if (t == 0) v *= 0.18033688f;  // 0.125*log2(e)
            size_t base =
                (((size_t)t * BB + b) * HH + hh) * ((size_t)SS * HEADK);
            Cbf[base + (size_t)s * HEADK + kk2] = f2bf(v);
          }
        }
      }
    } else {
      __syncthreads();
#pragma unroll
      for (int j = 0; j < 4; ++j) {
        int c = wn * 64 + j * 16 + l15;
        float bv = bias[tn0 + c];
#pragma unroll
        for (int i = 0; i < MI; ++i) {
          int row0 = wm * (TM / 2) + i * 16 + quad * 4;
          uint2v dw;
          dw[0] = pkbf_rne(acc[i][j][0] + bv, acc[i][j][1] + bv);
          dw[1] = pkbf_rne(acc[i][j][2] + bv, acc[i][j][3] + bv);
          int rb = row0 >> 3;
          *(uint2v*)(&smem[c * 128 + (((rb ^ (c & 15)) << 3) | (row0 & 7))]) =
              dw;
        }
      }
      __syncthreads();
      const int rb2 = lane & 15;
      const int cg = lane >> 4;
#pragma unroll
      for (int it = 0; it < 8; ++it) {
        int c = wv * 32 + it * 4 + cg;
        short8 vv = *(const short8*)(&smem[c * 128 + ((rb2 ^ (c & 15)) << 3)]);
        int gcol = tn0 + c;
        int hh = (gcol >> 6) & 15, kk2 = gcol & 63;
        int grow = tm0 + rb2 * 8;
        int b = grow >> 11, s = grow & 2047;
        size_t base = (((size_t)2 * BB + b) * HH + hh) * ((size_t)SS * HEADK);
        *(short8*)(&Cbf[base + (size_t)kk2 * SS + s]) = vv;
      }
    }
  }
}

// ---------------- flash attention, KV-split ----------------
// grid (16,16,4): qt=bx (128 q-rows), h=by, z: b=z>>1, ns=z&1 (KV half).
// 4 waves x 32 q-rows; KV tile 32, double-buffered (LDS 24 KB -> 4 blocks/CU
// = 4 waves/SIMD, 2x round-11 occupancy — the latency-bound fix).
// Max-free exp2 softmax => partials exactly additive: block writes
// unnormalized O^T (bf16, split ns -> Op0/Op1) + l (fp32); reduce combines.
__global__ __launch_bounds__(256, 4) void attn_kernel(
    const ushort_t* __restrict__ qkv, ushort_t* __restrict__ Op0,
    ushort_t* __restrict__ Op1, float* __restrict__ Lp) {
  __shared__ ushort_t Kt[2][32 * 64];   // [pos32][feat64], XOR-swizzled
  __shared__ ushort_t Vt[2][64 * 32];   // [feat64][pos32], XOR-swizzled
  __shared__ ushort_t Pw[4][32 * 32];   // per-wave P; reused 16x64 in epilogue

  const int qt = blockIdx.x, h = blockIdx.y;
  const int b = blockIdx.z >> 1, ns = blockIdx.z & 1;
  const int tid = threadIdx.x;
  const int wv = tid >> 6, lane = tid & 63;
  const int l15 = lane & 15, quad = lane >> 4;

  const size_t hstride = (size_t)SS * HEADK;
  const ushort_t* Qg = qkv + ((size_t)(0 * BB + b) * HH + h) * hstride;
  const ushort_t* Kg = qkv + ((size_t)(1 * BB + b) * HH + h) * hstride;
  const ushort_t* Vg = qkv + ((size_t)(2 * BB + b) * HH + h) * hstride; // [64][2048]
  ushort_t* Opp = ns ? Op1 : Op0;

  short8 qf[2][2];
#pragma unroll
  for (int mi = 0; mi < 2; ++mi)
#pragma unroll
    for (int kc = 0; kc < 2; ++kc)
      qf[mi][kc] = *(const short8*)(
          Qg + (size_t)(qt * 128 + wv * 32 + mi * 16 + l15) * 64 + kc * 32 +
          quad * 8);

  const short ONE = (short)0x3F80;
  short8 ones = {ONE, ONE, ONE, ONE, ONE, ONE, ONE, ONE};

  f32x4 oat[2][4];  // O^T rows feat=cf*16+quad*4+r, col qrow=l15
  f32x4 loa[2];
#pragma unroll
  for (int mi = 0; mi < 2; ++mi) {
    loa[mi] = (f32x4){0.f, 0.f, 0.f, 0.f};
#pragma unroll
    for (int c = 0; c < 4; ++c) oat[mi][c] = (f32x4){0.f, 0.f, 0.f, 0.f};
  }

  const int lrow = lane >> 3, gcb = (lane & 7) ^ lrow;   // K staging
  const int vfl = lane >> 2;                              // V staging feat 0..15
  const int vgb = (lane & 3) ^ ((vfl >> 1) & 3);          // V global pos-block

  const int pos0 = ns * (SS / 2);

  auto stage = [&](int jj, int db) {
    glds16(Kg + (size_t)(pos0 + jj * 32 + wv * 8 + lrow) * 64 + gcb * 8,
           &Kt[db][wv * 512]);
    glds16(Vg + (size_t)(wv * 16 + vfl) * SS + pos0 + jj * 32 + vgb * 8,
           &Vt[db][wv * 512]);
  };

  stage(0, 0);

  for (int j = 0; j < 32; ++j) {
    const int db = j & 1;
    __syncthreads();
    if (j + 1 < 32) stage(j + 1, db ^ 1);

    // S^T frags: rows pos = cf*16+quad*4+r (cf 0..1), col qrow = l15
    f32x4 st[2][2];
#pragma unroll
    for (int cf = 0; cf < 2; ++cf) {
      int n = cf * 16 + l15;
      short8 kf0 = *(const short8*)(&Kt[db][n * 64 + ((quad ^ (n & 7)) << 3)]);
      short8 kf1 =
          *(const short8*)(&Kt[db][n * 64 + (((quad + 4) ^ (n & 7)) << 3)]);
#pragma unroll
      for (int mi = 0; mi < 2; ++mi) {
        f32x4 z = (f32x4){0.f, 0.f, 0.f, 0.f};
        z = __builtin_amdgcn_mfma_f32_16x16x32_bf16(kf0, qf[mi][0], z, 0, 0, 0);
        z = __builtin_amdgcn_mfma_f32_16x16x32_bf16(kf1, qf[mi][1], z, 0, 0, 0);
        st[mi][cf] = z;
      }
    }

    // P = exp2(S^T) -> per-wave LDS [qrow32][pos32], swizzle (qrow>>1)&3
#pragma unroll
    for (int mi = 0; mi < 2; ++mi)
#pragma unroll
      for (int cf = 0; cf < 2; ++cf) {
        float e0 = EXP2F(st[mi][cf][0]);
        float e1 = EXP2F(st[mi][cf][1]);
        float e2 = EXP2F(st[mi][cf][2]);
        float e3 = EXP2F(st[mi][cf][3]);
        uint2v dw;
        dw[0] = pkbf_trunc(e0, e1);
        dw[1] = pkbf_trunc(e2, e3);
        int row = mi * 16 + l15;
        int pb = 2 * cf + (quad >> 1);
        int pbs = pb ^ ((l15 >> 1) & 3);
        *(uint2v*)(&Pw[wv][row * 32 + pbs * 8 + (quad & 1) * 4]) = dw;
      }

    // P as B-operand frags (row qrow=l15, k=pos 0..31)
    short8 pa[2];
#pragma unroll
    for (int mi = 0; mi < 2; ++mi) {
      int row = mi * 16 + l15;
      pa[mi] = *(const short8*)(&Pw[wv][row * 32 +
                                        ((quad ^ ((l15 >> 1) & 3)) << 3)]);
    }

    // O^T += V^T * P ; l += ones * P
#pragma unroll
    for (int cf = 0; cf < 4; ++cf) {
      short8 vf = *(const short8*)(&Vt[db][(cf * 16 + l15) * 32 +
                                           ((quad ^ ((l15 >> 1) & 3)) << 3)]);
#pragma unroll
      for (int mi = 0; mi < 2; ++mi)
        oat[mi][cf] = __builtin_amdgcn_mfma_f32_16x16x32_bf16(
            vf, pa[mi], oat[mi][cf], 0, 0, 0);
    }
#pragma unroll
    for (int mi = 0; mi < 2; ++mi)
      loa[mi] = __builtin_amdgcn_mfma_f32_16x16x32_bf16(ones, pa[mi], loa[mi],
                                                        0, 0, 0);
  }

  // epilogue: unnormalized O^T -> [qrow][feat] via per-wave Pw slab (16x64)
  const size_t obase = ((size_t)b * HH + h) * SS * HEADK;  // Opp[b][h][qrow][64]
#pragma unroll
  for (int mi = 0; mi < 2; ++mi) {
#pragma unroll
    for (int cf = 0; cf < 4; ++cf) {
      uint2v dw;
      dw[0] = pkbf_rne(oat[mi][cf][0], oat[mi][cf][1]);
      dw[1] = pkbf_rne(oat[mi][cf][2], oat[mi][cf][3]);
      int cb = 2 * cf + (quad >> 1);
      int cbs = cb ^ (l15 & 7);
      *(uint2v*)(&Pw[wv][l15 * 64 + cbs * 8 + (quad & 1) * 4]) = dw;
    }
    // same-wave DS ops are ordered: reads below see the writes above
    const int r = lane >> 2;
#pragma unroll
    for (int pass = 0; pass < 2; ++pass) {
      int g = (lane & 3) + 4 * pass;
      short8 ov = *(const short8*)(&Pw[wv][r * 64 + ((g ^ (r & 7)) << 3)]);
      int qrow = qt * 128 + wv * 32 + mi * 16 + r;
      *(short8*)(&Opp[obase + (size_t)qrow * 64 + g * 8]) = ov;
    }
    if (quad == 0) {
      int qrow = qt * 128 + wv * 32 + mi * 16 + l15;
      Lp[((size_t)(ns * BB + b) * HH + h) * SS + qrow] = loa[mi][0];
    }
  }
}

// ---------------- combine the 2 KV-split partials ----------------
__global__ void reduce_kernel(const ushort_t* __restrict__ Op0,
                              const ushort_t* __restrict__ Op1,
                              const float* __restrict__ Lp,
                              ushort_t* __restrict__ ob) {
  const size_t nsL = (size_t)BB * HH * SS;
  int c = blockIdx.x * blockDim.x + threadIdx.x;     // 8-elem chunk id
  int fc = c & 7;
  int hh = (c >> 3) & 15;
  int row = c >> 7;                                  // b*2048 + s
  int b = row >> 11, s = row & 2047;
  size_t po = (((size_t)b * HH + hh) * SS + s) * 64 + fc * 8;
  uint2v a0 = *(const uint2v*)(&Op0[po]);
  uint2v a1 = *(const uint2v*)(&Op0[po + 4]);
  uint2v b0 = *(const uint2v*)(&Op1[po]);
  uint2v b1 = *(const uint2v*)(&Op1[po + 4]);
  size_t lo = ((size_t)b * HH + hh) * SS + s;
  float inv = 1.0f / (Lp[lo] + Lp[nsL + lo]);
  uint2v o0, o1;
  o0[0] = pkbf_rne((bflo2f(a0[0]) + bflo2f(b0[0])) * inv,
                   (bfhi2f(a0[0]) + bfhi2f(b0[0])) * inv);
  o0[1] = pkbf_rne((bflo2f(a0[1]) + bflo2f(b0[1])) * inv,
                   (bfhi2f(a0[1]) + bfhi2f(b0[1])) * inv);
  o1[0] = pkbf_rne((bflo2f(a1[0]) + bflo2f(b1[0])) * inv,
                   (bfhi2f(a1[0]) + bfhi2f(b1[0])) * inv);
  o1[1] = pkbf_rne((bflo2f(a1[1]) + bflo2f(b1[1])) * inv,
                   (bfhi2f(a1[1]) + bfhi2f(b1[1])) * inv);
  size_t oo = ((size_t)(b * SS + s)) * DDIM + hh * 64 + fc * 8;
  *(uint2v*)(&ob[oo]) = o0;
  *(uint2v*)(&ob[oo + 4]) = o1;
}

extern "C" void kernel_launch(void* const* d_in, const int* in_sizes, int n_in,
                              void* d_out, int out_size, void* d_ws,
                              size_t ws_size, hipStream_t stream) {
  const float* x = (const float*)d_in[0];
  const float* Wqkv = (const float*)d_in[1];
  const float* bqkv = (const float*)d_in[2];
  const float* Wproj = (const float*)d_in[3];
  const float* bproj = (const float*)d_in[4];
  float* out = (float*)d_out;

  // Workspace plan (peak 50.33 MB, identical to proven rounds 1-11):
  //   [0      .. 4.19M)  xb   (GEMM1 A)      -> reused as Op0 by attn
  //   [4.19M  .. 7.34M)  wqb  (GEMM1 B)      -> reused as Lp by attn
  //   [7.34M  .. 8.39M)  wpb  (GEMM2 B, alive throughout)
  //   [8.39M  .. 20.97M) qkvb (attn input)   -> reused as obuf by reduce
  //   [20.97M .. 25.17M) Op1
  ushort_t* xb = (ushort_t*)d_ws;
  ushort_t* wqb = xb + (size_t)4096 * 1024;
  ushort_t* wpb = wqb + (size_t)3072 * 1024;
  ushort_t* qkvb = wpb + (size_t)1024 * 1024;
  ushort_t* Op1 = qkvb + (size_t)3 * BB * HH * SS * HEADK;
  ushort_t* Op0 = xb;
  float* Lp = (float*)wqb;
  ushort_t* obuf = qkvb;

  const int n0 = 4096 * 1024 / 4, n1 = 3072 * 1024 / 4, n2 = 1024 * 1024 / 4;
  cvt3_kernel<<<(n0 + n1 + n2 + 255) / 256, 256, 0, stream>>>(
      x, xb, n0, Wqkv, wqb, n1, Wproj, wpb, n2);
  gemm_nt<0, 128><<<dim3(3072 / 128, 4096 / 128), 256, 0, stream>>>(
      xb, wqb, bqkv, nullptr, qkvb, 4096, 3072, 1024);
  attn_kernel<<<dim3(16, 16, 4), 256, 0, stream>>>(qkvb, Op0, Op1, Lp);
  reduce_kernel<<<(BB * SS * DDIM / 8) / 256, 256, 0, stream>>>(Op0, Op1, Lp,
                                                                obuf);
  gemm_nt<1, 64><<<dim3(1024 / 128, 4096 / 64), 256, 0, stream>>>(
      obuf, wpb, bproj, out, nullptr, 4096, 1024, 1024);
}